// Round 18
// baseline (31.276 us; speedup 1.0000x reference)
//
#include <hip/hip_runtime.h>
#include <stdint.h>

#define NANCH   8192
#define NCLS    80
#define IMW     1024
#define IMH     1024
#define MAXDET  100
#define SCORE_TH 0.05f
#define TAU      0.999691f     // E[survivors] ~= 200 per batch (sigma ~14)
#define CAP      256           // P(c>256) ~ 3e-5; overflow -> exact fallback
#define KSENT    0x7FFFFFF0
#define ROWS_PB  64            // decode rows per block (4 threads per row)

// key: [63:32] monotonic(score) | [31:16] ~idx (stable tie-break) | [15:0] class
// meta: 4 x int16 box coords
__device__ __forceinline__ float key_score(uint64_t key) {
    uint32_t m = (uint32_t)(key >> 32);
    uint32_t bits = (m & 0x80000000u) ? (m & 0x7FFFFFFFu) : ~m;
    return __uint_as_float(bits);
}

// shared decode math (exact, _rn blocks fma contraction) -> (key, meta)
__device__ __forceinline__ void decode_one(const float4 r, const float4 a,
                                           uint32_t mono32, int bj, int n,
                                           uint64_t& key, uint64_t& meta) {
    float awx = __fsub_rn(a.z, a.x);
    float awy = __fsub_rn(a.w, a.y);
    float acx = __fadd_rn(a.x, __fmul_rn(0.5f, awx));
    float acy = __fadd_rn(a.y, __fmul_rn(0.5f, awy));
    float rx = __fmul_rn(r.x, 0.1f);
    float ry = __fmul_rn(r.y, 0.1f);
    float rw = __fmul_rn(r.z, 0.2f);
    float rh = __fmul_rn(r.w, 0.2f);
    float pwx = __fmul_rn(expf(rw), awx);
    float pwy = __fmul_rn(expf(rh), awy);
    float pcx = __fadd_rn(__fmul_rn(rx, awx), acx);
    float pcy = __fadd_rn(__fmul_rn(ry, awy), acy);

    int x1 = (int)__fsub_rn(pcx, __fmul_rn(0.5f, pwx));
    int y1 = (int)__fsub_rn(pcy, __fmul_rn(0.5f, pwy));
    int x2 = (int)__fadd_rn(pcx, __fmul_rn(0.5f, pwx));
    int y2 = (int)__fadd_rn(pcy, __fmul_rn(0.5f, pwy));
    x1 = max(x1, 0);
    y1 = max(y1, 0);
    x2 = min(x2, IMW - 1);
    y2 = min(y2, IMH - 1);

    key = ((uint64_t)mono32 << 32)
        | ((uint64_t)((~(uint32_t)n) & 0xFFFFu) << 16)
        | (uint64_t)(uint32_t)bj;
    meta = (uint64_t)(uint16_t)x1
         | ((uint64_t)(uint16_t)y1 << 16)
         | ((uint64_t)(uint16_t)x2 << 32)
         | ((uint64_t)(uint16_t)y2 << 48);
}

// ---------------- Kernel 1: decode, 4 thr/row, writes only survivors (+cnt) ----------------
__global__ __launch_bounds__(256)
void decode_kernel(const float* __restrict__ cls_heads,
                   const float* __restrict__ reg_heads,
                   const float* __restrict__ anchors,
                   int* __restrict__ cnt,
                   ulonglong2* __restrict__ surv) {
    const int tid  = threadIdx.x;
    const int lane = tid & 63;
    const int part = tid & 3;              // 4 threads per row
    const int b    = blockIdx.y;
    const int n    = blockIdx.x * ROWS_PB + (tid >> 2);
    const int row  = b * NANCH + n;

    // coalesced: wave = 16 rows x 64B contiguous segments per load
    float best = -1e30f; int bestj = 0;
    {
        const float* rp = cls_heads + (size_t)row * NCLS;
#pragma unroll
        for (int k = 0; k < 5; ++k) {
            int j0 = part * 4 + k * 16;
            float4 v = *reinterpret_cast<const float4*>(rp + j0);
            if (v.x > best) { best = v.x; bestj = j0 + 0; }
            if (v.y > best) { best = v.y; bestj = j0 + 1; }
            if (v.z > best) { best = v.z; bestj = j0 + 2; }
            if (v.w > best) { best = v.w; bestj = j0 + 3; }
        }
    }
    // 4-lane (max, first-occurrence argmax) reduce; packed = mono<<8 | (255-j)
    uint32_t ub = __float_as_uint(best);
    uint32_t mono = (ub & 0x80000000u) ? ~ub : (ub | 0x80000000u);
    uint64_t kk = ((uint64_t)mono << 8) | (uint64_t)(255 - bestj);
    {
        uint64_t o = __shfl_xor(kk, 1); if (o > kk) kk = o;
        o = __shfl_xor(kk, 2); if (o > kk) kk = o;
    }

    uint64_t key = 0, meta = 0;
    bool svv = false;
    if (part == 0) {
        uint32_t mono32 = (uint32_t)(kk >> 8);
        uint32_t mono_tau = __float_as_uint(TAU) | 0x80000000u;
        if (mono32 > mono_tau) {           // == best > TAU — decode only survivors
            int bj = 255 - (int)(kk & 0xFF);
            float4 r = reinterpret_cast<const float4*>(reg_heads)[row];
            float4 a = reinterpret_cast<const float4*>(anchors)[row];
            decode_one(r, a, mono32, bj, n, key, meta);
            svv = true;
        }
    }

    // flat compaction: one atomic per wave (order nondet; k2 rank-sort restores)
    uint64_t mask = __ballot(svv);
    int rank = __popcll(mask & ((1ULL << lane) - 1ULL));
    int base = 0;
    if (lane == 0 && mask) base = atomicAdd(cnt + b, __popcll(mask));
    base = __shfl(base, 0);
    if (svv) {
        int p = base + rank;
        if (p < CAP) surv[(size_t)b * CAP + p] = make_ulonglong2(key, meta);
    }
}

// ---------------- fallback helper (cold path, exact) ----------------
struct Kept {
    float x1[2], y1[2], x2[2], y2[2], ar[2];
    int   cl[2];
};

__device__ __forceinline__ void nms_try_keep(uint64_t key, uint64_t meta, float s,
                                             int lane, int& nk, Kept& K,
                                             float* __restrict__ out, int b) {
    int cls = (int)(key & 0xFFFFu);
    float cx1 = (float)(short)(meta & 0xFFFFu);
    float cy1 = (float)(short)((meta >> 16) & 0xFFFFu);
    float cx2 = (float)(short)((meta >> 32) & 0xFFFFu);
    float cy2 = (float)(short)((meta >> 48) & 0xFFFFu);
    float ca = fmaxf(cx2 - cx1, 0.f) * fmaxf(cy2 - cy1, 0.f);

    bool supp = false;
#pragma unroll
    for (int r = 0; r < 2; ++r) {
        int slot = lane + 64 * r;
        if (slot < nk && K.cl[r] == cls) {
            float ix1 = fmaxf(K.x1[r], cx1), iy1 = fmaxf(K.y1[r], cy1);
            float ix2 = fminf(K.x2[r], cx2), iy2 = fminf(K.y2[r], cy2);
            float inter = fmaxf(ix2 - ix1, 0.f) * fmaxf(iy2 - iy1, 0.f);
            if (3.f * inter > K.ar[r] + ca) supp = true;   // exact iou>0.5
        }
    }
    if (__ballot(supp) != 0ULL) return;

    int rr = nk >> 6, l = nk & 63;
    if (lane == l) {
        if (rr == 0) { K.x1[0]=cx1; K.y1[0]=cy1; K.x2[0]=cx2; K.y2[0]=cy2; K.ar[0]=ca; K.cl[0]=cls; }
        else         { K.x1[1]=cx1; K.y1[1]=cy1; K.x2[1]=cx2; K.y2[1]=cy2; K.ar[1]=ca; K.cl[1]=cls; }
    }
    if (lane == 0) {
        out[b * MAXDET + nk] = s;
        out[2 * MAXDET + b * MAXDET + nk] = (float)cls;
        float* ob = out + 4 * MAXDET + (size_t)(b * MAXDET + nk) * 4;
        ob[0] = cx1; ob[1] = cy1; ob[2] = cx2; ob[3] = cy2;
    }
    ++nk;
}

// ---------------- Kernel 2: rank-sort (256 thr) + BARRIER-FREE single-wave NMS ----------------
__global__ __launch_bounds__(256)
void sort_nms_kernel(const int* __restrict__ cnt,
                     const float* __restrict__ cls_heads,
                     const float* __restrict__ reg_heads,
                     const float* __restrict__ anchors,
                     uint64_t* __restrict__ wk,      // fallback scratch only
                     uint64_t* __restrict__ wm,
                     const ulonglong2* __restrict__ surv,
                     float* __restrict__ out) {
    __shared__ __align__(16) ulonglong2 sq[CAP];
    __shared__ __align__(16) uint64_t skey[CAP + 16];
    __shared__ float4 kept_box[128];
    __shared__ float  kept_area[128];
    __shared__ int    kept_cls[128];
    __shared__ float4 sbox[64];
    __shared__ float  sarea[64];
    __shared__ int    scls[64];
    __shared__ uint64_t fbmap[NANCH / 64];

    const int b = blockIdx.x;
    const int tid = threadIdx.x;
    const int lane = tid & 63;

    // parallel cold loads (1 survivor per thread; cnt alongside)
    ulonglong2 v0 = surv[(size_t)b * CAP + tid];
    int c = cnt[b];

    bool overflow = (c > CAP) || (c < 0);
    if (overflow) c = 0;
    const int cpad   = (c + 63) & ~63;
    const int cpad16 = (c + 15) & ~15;

    skey[tid] = (tid < c) ? v0.x : 0ULL;
    if (tid < 128) kept_cls[tid] = KSENT;
    __syncthreads();

    // rank-order sort: one scan, register-held element (keys unique => exact)
    if (tid < c) {
        uint64_t k0 = v0.x;
        int r = 0;
        for (int j0 = 0; j0 < cpad16; j0 += 16) {
            int acc = 0;
#pragma unroll
            for (int u = 0; u < 8; ++u) {
                ulonglong2 pr = *reinterpret_cast<const ulonglong2*>(&skey[j0 + 2 * u]);
                acc += (int)(pr.x > k0) + (int)(pr.y > k0);
            }
            r += acc;
        }
        sq[r] = v0;
    }
    for (int i = c + tid; i < cpad; i += 256) sq[i] = make_ulonglong2(0ULL, 0ULL);
    __syncthreads();          // the ONLY block-wide barrier

    if (tid >= 64) return;    // wave 0 does everything below — zero barriers

    // ---- single-wave batched greedy NMS (nk/done in uniform registers) ----
    int nk = 0;
    bool done = false;
    bool need_fb = overflow;

    for (int p0 = 0; p0 < cpad && !done; p0 += 64) {
        ulonglong2 kv = sq[p0 + lane];
        uint64_t key = kv.x, meta = kv.y;
        float s = key_score(key);               // pad key=0 -> NaN -> invalid
        bool sval = (s > SCORE_TH);
        int cls_c = sval ? (int)(key & 0xFFFFu) : -1;
        float cx1 = (float)(short)(meta & 0xFFFFu);
        float cy1 = (float)(short)((meta >> 16) & 0xFFFFu);
        float cx2 = (float)(short)((meta >> 32) & 0xFFFFu);
        float cy2 = (float)(short)((meta >> 48) & 0xFFFFu);
        float ca = fmaxf(cx2 - cx1, 0.f) * fmaxf(cy2 - cy1, 0.f);

        // stage unpacked batch for the intra-batch pass (same wave: in-order LDS)
        sbox[lane]  = make_float4(cx1, cy1, cx2, cy2);
        sarea[lane] = ca;
        scls[lane]  = sval ? (int)(key & 0xFFFFu) : 0x7FFF;
        __builtin_amdgcn_wave_barrier();

        // vs previously-kept set — 8-wide batched LDS reads, sentinel-padded
        bool supk = false;
        int nkp = (nk + 7) & ~7;
        for (int j0 = 0; j0 < nkp; j0 += 8) {
#pragma unroll
            for (int u = 0; u < 8; ++u) {
                float4 kb = kept_box[j0 + u];
                float ka = kept_area[j0 + u];
                int kc = kept_cls[j0 + u];
                float ix1 = fmaxf(kb.x, cx1), iy1 = fmaxf(kb.y, cy1);
                float ix2 = fminf(kb.z, cx2), iy2 = fminf(kb.w, cy2);
                float inter = fmaxf(ix2 - ix1, 0.f) * fmaxf(iy2 - iy1, 0.f);
                supk |= (kc == cls_c) & (3.f * inter > ka + ca);
            }
        }
        bool alive0 = sval && !supk;

        // intra-batch pairwise suppression (staged LDS broadcast reads)
        uint64_t supBy = 0;
        for (int t0 = 0; t0 < 64; t0 += 8) {
#pragma unroll
            for (int u = 0; u < 8; ++u) {
                int t = t0 + u;
                float4 tb = sbox[t];
                float ta = sarea[t];
                int tcls = scls[t];
                float ix1 = fmaxf(tb.x, cx1), iy1 = fmaxf(tb.y, cy1);
                float ix2 = fminf(tb.z, cx2), iy2 = fminf(tb.w, cy2);
                float inter = fmaxf(ix2 - ix1, 0.f) * fmaxf(iy2 - iy1, 0.f);
                bool sup = (t < lane) && (tcls == cls_c) && (3.f * inter > ta + ca);
                supBy |= ((uint64_t)sup) << t;
            }
        }

        uint64_t aliveCand = __ballot(alive0);
        uint64_t aliveMask;
        if (__ballot(supBy != 0ULL) == 0ULL) {
            aliveMask = aliveCand;          // fast path: no intra-batch suppression
        } else {
            uint64_t killed = 0;
            for (int t = 0; t < 64; ++t) {
                uint64_t kill_t = __ballot((supBy >> t) & 1ULL);
                bool talive = ((aliveCand >> t) & 1ULL) && !((killed >> t) & 1ULL);
                if (talive) killed |= kill_t;
            }
            aliveMask = aliveCand & ~killed;
        }

        int myrank = __popcll(aliveMask & ((1ULL << lane) - 1ULL));
        bool keepme = ((aliveMask >> lane) & 1ULL) && (nk + myrank < MAXDET);
        if (keepme) {
            int slot = nk + myrank;
            kept_box[slot]  = make_float4(cx1, cy1, cx2, cy2);
            kept_area[slot] = ca;
            kept_cls[slot]  = cls_c;
            out[b * MAXDET + slot] = s;
            out[2 * MAXDET + b * MAXDET + slot] = (float)cls_c;
            float* ob = out + 4 * MAXDET + (size_t)(b * MAXDET + slot) * 4;
            ob[0] = cx1; ob[1] = cy1; ob[2] = cx2; ob[3] = cy2;
        }
        __builtin_amdgcn_wave_barrier();    // kept writes ordered before next iter reads

        int navail = __popcll(aliveMask);
        int room = MAXDET - nk;
        nk += (navail < room) ? navail : room;   // uniform across wave

        uint64_t invalid = __ballot(!sval);
        if (nk >= MAXDET) done = true;
        else if (invalid) { need_fb = true; done = true; }  // exhausted short
    }
    if (!done && nk < MAXDET) need_fb = true;

    // ---- cold exact fallback (never taken on this input): recompute + extraction ----
    if (need_fb) {
        uint64_t* wkb = wk + (size_t)b * NANCH;
        uint64_t* wmb = wm + (size_t)b * NANCH;
        for (int n2 = lane; n2 < NANCH; n2 += 64) {
            int row2 = b * NANCH + n2;
            const float* rp = cls_heads + (size_t)row2 * NCLS;
            float best = -1e30f; int bj = 0;
            for (int j = 0; j < NCLS; ++j) {       // first-occurrence argmax
                float v = rp[j];
                if (v > best) { best = v; bj = j; }
            }
            uint32_t ub = __float_as_uint(best);
            uint32_t mono32 = (ub & 0x80000000u) ? ~ub : (ub | 0x80000000u);
            float4 r = reinterpret_cast<const float4*>(reg_heads)[row2];
            float4 a = reinterpret_cast<const float4*>(anchors)[row2];
            uint64_t key2, meta2;
            decode_one(r, a, mono32, bj, n2, key2, meta2);
            wkb[n2] = key2;
            wmb[n2] = meta2;
        }
        for (int i = lane; i < NANCH / 64; i += 64) fbmap[i] = 0ULL;
        __builtin_amdgcn_wave_barrier();

        nk = 0;
        Kept K;
        K.cl[0] = K.cl[1] = -1;
        K.x1[0]=K.y1[0]=K.x2[0]=K.y2[0]=K.ar[0]=0.f;
        K.x1[1]=K.y1[1]=K.x2[1]=K.y2[1]=K.ar[1]=0.f;

        for (int iter = 0; iter < NANCH; ++iter) {
            uint64_t mybest = 0; int myq = -1;
            for (int q = lane; q < NANCH; q += 64) {
                bool cons = (fbmap[q >> 6] >> (q & 63)) & 1ULL;
                uint64_t kk2 = wkb[q];
                if (!cons && kk2 > mybest) { mybest = kk2; myq = q; }
            }
            uint64_t best2 = mybest;
#pragma unroll
            for (int j = 32; j; j >>= 1) {
                uint64_t o = __shfl_xor(best2, j);
                if (o > best2) best2 = o;
            }
            if (best2 == 0ULL) break;
            float s = key_score(best2);
            if (!(s > SCORE_TH)) break;
            uint64_t msk = __ballot(mybest == best2);
            int wl = __ffsll((unsigned long long)msk) - 1;
            int q = __shfl(myq, wl);
            if (lane == wl) fbmap[q >> 6] |= (1ULL << (q & 63));
            uint64_t cm = wmb[q];
            nms_try_keep(best2, cm, s, lane, nk, K, out, b);
            if (nk == MAXDET) break;
            __builtin_amdgcn_wave_barrier();
        }
    }

    // pad remaining slots with -1
    for (int t = nk + lane; t < MAXDET; t += 64) {
        out[b * MAXDET + t] = -1.f;
        out[2 * MAXDET + b * MAXDET + t] = -1.f;
        float* ob = out + 4 * MAXDET + (size_t)(b * MAXDET + t) * 4;
        ob[0] = -1.f; ob[1] = -1.f; ob[2] = -1.f; ob[3] = -1.f;
    }
}

extern "C" void kernel_launch(void* const* d_in, const int* in_sizes, int n_in,
                              void* d_out, int out_size, void* d_ws, size_t ws_size,
                              hipStream_t stream) {
    (void)in_sizes; (void)n_in; (void)out_size; (void)ws_size;
    const float* cls_heads = (const float*)d_in[0];
    const float* reg_heads = (const float*)d_in[1];
    const float* anchors   = (const float*)d_in[2];
    float* out = (float*)d_out;

    char* w = (char*)d_ws;
    int*        cnt  = (int*)w;                                  // 8 B (zeroed per replay)
    uint64_t*   wk   = (uint64_t*)(w + 1024);                    // 128 KiB fallback scratch
    uint64_t*   wm   = (uint64_t*)(w + 1024 + 131072);           // 128 KiB fallback scratch
    ulonglong2* surv = (ulonglong2*)(w + 1024 + 262144);         // 8 KiB

    hipMemsetAsync(cnt, 0, 2 * sizeof(int), stream);
    decode_kernel<<<dim3(NANCH / ROWS_PB, 2), 256, 0, stream>>>(cls_heads, reg_heads, anchors,
                                                                cnt, surv);
    sort_nms_kernel<<<dim3(2), 256, 0, stream>>>(cnt, cls_heads, reg_heads, anchors,
                                                 wk, wm, surv, out);
}

// Round 19
// 23.459 us; speedup vs baseline: 1.3332x; 1.3332x over previous
//
#include <hip/hip_runtime.h>
#include <stdint.h>

#define NANCH   8192
#define NCLS    80
#define IMW     1024
#define IMH     1024
#define MAXDET  100
#define SCORE_TH 0.05f
#define TAU      0.999691f     // E[survivors] ~= 200 per batch (sigma ~14)
#define CAP      512           // overflow -> exact fallback
#define KSENT    0x7FFFFFF0
#define ROWS_PB  128           // decode rows per block
#define LSTRIDE  84            // decode LDS slab stride (floats)

// key: [63:32] monotonic(score) | [31:16] ~idx (stable tie-break) | [15:0] class
// meta: 4 x int16 box coords
__device__ __forceinline__ float key_score(uint64_t key) {
    uint32_t m = (uint32_t)(key >> 32);
    uint32_t bits = (m & 0x80000000u) ? (m & 0x7FFFFFFFu) : ~m;
    return __uint_as_float(bits);
}

// ---------------- Kernel 1: decode + atomic flat compaction ----------------
__global__ __launch_bounds__(256)
void decode_kernel(const float* __restrict__ cls_heads,
                   const float* __restrict__ reg_heads,
                   const float* __restrict__ anchors,
                   int* __restrict__ cnt,
                   uint64_t* __restrict__ wk,
                   uint64_t* __restrict__ wm,
                   ulonglong2* __restrict__ surv) {
    __shared__ float slab[ROWS_PB * LSTRIDE];   // 42 KiB

    const int tid  = threadIdx.x;
    const int lane = tid & 63;
    const int b    = blockIdx.y;
    const int r0   = blockIdx.x * ROWS_PB;

    // coalesced stage of 128 rows x 80 cls into LDS
    {
        const float* gbase = cls_heads + ((size_t)b * NANCH + r0) * NCLS;
#pragma unroll
        for (int it = 0; it < (ROWS_PB * NCLS) / (256 * 4); ++it) {   // 10 iters
            int g = it * 1024 + tid * 4;
            float4 v = *reinterpret_cast<const float4*>(gbase + g);
            int row = g / NCLS, col = g % NCLS;
            *reinterpret_cast<float4*>(&slab[row * LSTRIDE + col]) = v;
        }
    }
    __syncthreads();

    if (tid >= ROWS_PB) return;

    const int n   = r0 + tid;
    const int row = b * NANCH + n;

    float best = -1e30f; int bestj = 0;
    {
        const float4* rp = reinterpret_cast<const float4*>(&slab[tid * LSTRIDE]);
#pragma unroll
        for (int k = 0; k < NCLS / 4; ++k) {
            float4 v = rp[k];
            if (v.x > best) { best = v.x; bestj = 4 * k + 0; }
            if (v.y > best) { best = v.y; bestj = 4 * k + 1; }
            if (v.z > best) { best = v.z; bestj = 4 * k + 2; }
            if (v.w > best) { best = v.w; bestj = 4 * k + 3; }
        }
    }

    float4 r = reinterpret_cast<const float4*>(reg_heads)[row];
    float4 a = reinterpret_cast<const float4*>(anchors)[row];

    // decode — _rn blocks fma contraction (trunc boundaries ulp-sensitive)
    float awx = __fsub_rn(a.z, a.x);
    float awy = __fsub_rn(a.w, a.y);
    float acx = __fadd_rn(a.x, __fmul_rn(0.5f, awx));
    float acy = __fadd_rn(a.y, __fmul_rn(0.5f, awy));
    float rx = __fmul_rn(r.x, 0.1f);
    float ry = __fmul_rn(r.y, 0.1f);
    float rw = __fmul_rn(r.z, 0.2f);
    float rh = __fmul_rn(r.w, 0.2f);
    float pwx = __fmul_rn(expf(rw), awx);
    float pwy = __fmul_rn(expf(rh), awy);
    float pcx = __fadd_rn(__fmul_rn(rx, awx), acx);
    float pcy = __fadd_rn(__fmul_rn(ry, awy), acy);

    int x1 = (int)__fsub_rn(pcx, __fmul_rn(0.5f, pwx));
    int y1 = (int)__fsub_rn(pcy, __fmul_rn(0.5f, pwy));
    int x2 = (int)__fadd_rn(pcx, __fmul_rn(0.5f, pwx));
    int y2 = (int)__fadd_rn(pcy, __fmul_rn(0.5f, pwy));
    x1 = max(x1, 0);
    y1 = max(y1, 0);
    x2 = min(x2, IMW - 1);
    y2 = min(y2, IMH - 1);

    uint32_t u = __float_as_uint(best);
    uint32_t mono = (u & 0x80000000u) ? ~u : (u | 0x80000000u);
    uint64_t key = ((uint64_t)mono << 32)
                 | ((uint64_t)((~(uint32_t)n) & 0xFFFFu) << 16)
                 | (uint64_t)(uint32_t)bestj;
    uint64_t meta = (uint64_t)(uint16_t)x1
                  | ((uint64_t)(uint16_t)y1 << 16)
                  | ((uint64_t)(uint16_t)x2 << 32)
                  | ((uint64_t)(uint16_t)y2 << 48);

    wk[row] = key;
    wm[row] = meta;

    // flat compaction: one atomic per wave; order nondeterministic, rank-sort
    // in k2 re-orders by unique key so final output is deterministic.
    bool svv = (best > TAU);
    uint64_t mask = __ballot(svv);
    int rank = __popcll(mask & ((1ULL << lane) - 1ULL));
    int base = 0;
    if (lane == 0 && mask) base = atomicAdd(cnt + b, __popcll(mask));
    base = __shfl(base, 0);
    if (svv) {
        int p = base + rank;
        if (p < CAP) surv[(size_t)b * CAP + p] = make_ulonglong2(key, meta);
    }
}

// ---------------- fallback helper (cold path, exact) ----------------
struct Kept {
    float x1[2], y1[2], x2[2], y2[2], ar[2];
    int   cl[2];
};

__device__ __forceinline__ void nms_try_keep(uint64_t key, uint64_t meta, float s,
                                             int lane, int& nk, Kept& K,
                                             float* __restrict__ out, int b) {
    int cls = (int)(key & 0xFFFFu);
    float cx1 = (float)(short)(meta & 0xFFFFu);
    float cy1 = (float)(short)((meta >> 16) & 0xFFFFu);
    float cx2 = (float)(short)((meta >> 32) & 0xFFFFu);
    float cy2 = (float)(short)((meta >> 48) & 0xFFFFu);
    float ca = fmaxf(cx2 - cx1, 0.f) * fmaxf(cy2 - cy1, 0.f);

    bool supp = false;
#pragma unroll
    for (int r = 0; r < 2; ++r) {
        int slot = lane + 64 * r;
        if (slot < nk && K.cl[r] == cls) {
            float ix1 = fmaxf(K.x1[r], cx1), iy1 = fmaxf(K.y1[r], cy1);
            float ix2 = fminf(K.x2[r], cx2), iy2 = fminf(K.y2[r], cy2);
            float inter = fmaxf(ix2 - ix1, 0.f) * fmaxf(iy2 - iy1, 0.f);
            if (3.f * inter > K.ar[r] + ca) supp = true;
        }
    }
    if (__ballot(supp) != 0ULL) return;

    int rr = nk >> 6, l = nk & 63;
    if (lane == l) {
        if (rr == 0) { K.x1[0]=cx1; K.y1[0]=cy1; K.x2[0]=cx2; K.y2[0]=cy2; K.ar[0]=ca; K.cl[0]=cls; }
        else         { K.x1[1]=cx1; K.y1[1]=cy1; K.x2[1]=cx2; K.y2[1]=cy2; K.ar[1]=ca; K.cl[1]=cls; }
    }
    if (lane == 0) {
        out[b * MAXDET + nk] = s;
        out[2 * MAXDET + b * MAXDET + nk] = (float)cls;
        float* ob = out + 4 * MAXDET + (size_t)(b * MAXDET + nk) * 4;
        ob[0] = cx1; ob[1] = cy1; ob[2] = cx2; ob[3] = cy2;
    }
    ++nk;
}

// ---------------- Kernel 2: load + rank-sort + 4-wave cooperative NMS ----------------
__global__ __launch_bounds__(256)
void sort_nms_kernel(const int* __restrict__ cnt,
                     const uint64_t* __restrict__ wk,
                     const uint64_t* __restrict__ wm,
                     const ulonglong2* __restrict__ surv,
                     float* __restrict__ out) {
    __shared__ __align__(16) ulonglong2 sv_[CAP];
    __shared__ __align__(16) ulonglong2 sq[CAP];
    __shared__ __align__(16) uint64_t skey[CAP + 16];
    __shared__ float4 kept_box[128];
    __shared__ float  kept_area[128];
    __shared__ int    kept_cls[128];
    __shared__ uint64_t smask[4];       // per-wave supk ballot
    __shared__ uint64_t sby[4 * 64];    // per-wave partial supBy masks
    __shared__ int snk, sdone, sneedfb;
    __shared__ uint64_t fbmap[NANCH / 64];

    const int b = blockIdx.x;
    const int tid = threadIdx.x;
    const int lane = tid & 63;
    const int w = tid >> 6;

    int c = cnt[b];
    bool overflow = (c > CAP) || (c < 0);
    if (overflow) c = 0;                 // fallback handles
    const int cpad   = (c + 63) & ~63;
    const int cpad16 = (c + 15) & ~15;

    if (tid < 128) kept_cls[tid] = KSENT;
    if (tid == 0) { snk = 0; sdone = 0; sneedfb = overflow ? 1 : 0; }

    // load survivors (coalesced, <=2 iters)
    for (int i = tid; i < c; i += 256) {
        ulonglong2 v = surv[(size_t)b * CAP + i];
        sv_[i] = v; skey[i] = v.x;
    }
    for (int i = c + tid; i < cpad16; i += 256) skey[i] = 0ULL;
    __syncthreads();

    // rank-order sort (unique keys => exact descending), paired b128 key reads
    for (int i = tid; i < c; i += 256) {
        uint64_t ky = skey[i];
        int r = 0;
        for (int j0 = 0; j0 < cpad16; j0 += 16) {
            int acc = 0;
#pragma unroll
            for (int u = 0; u < 8; ++u) {
                ulonglong2 pr = *reinterpret_cast<const ulonglong2*>(&skey[j0 + 2 * u]);
                acc += (int)(pr.x > ky) + (int)(pr.y > ky);
            }
            r += acc;
        }
        sq[r] = sv_[i];
    }
    for (int i = c + tid; i < cpad; i += 256) sq[i] = make_ulonglong2(0ULL, 0ULL);
    // ordered by the loop-top barrier below

    // ---- batched greedy NMS, 4-wave cooperative ----
    for (int p0 = 0; p0 < cpad; p0 += 64) {
        __syncthreads();                        // kept/snk/sq visible to all waves
        if (sdone) break;                       // uniform (LDS)
        const int nk = snk;

        ulonglong2 kv = sq[p0 + lane];
        uint64_t key = kv.x, meta = kv.y;
        float s = key_score(key);               // pad key=0 -> NaN -> invalid
        bool sval = (s > SCORE_TH);
        int cls_c = sval ? (int)(key & 0xFFFFu) : -1;
        float cx1 = (float)(short)(meta & 0xFFFFu);
        float cy1 = (float)(short)((meta >> 16) & 0xFFFFu);
        float cx2 = (float)(short)((meta >> 32) & 0xFFFFu);
        float cy2 = (float)(short)((meta >> 48) & 0xFFFFu);
        float ca = fmaxf(cx2 - cx1, 0.f) * fmaxf(cy2 - cy1, 0.f);

        // kept-set test: wave w owns kept slots j == w (mod 4); sentinel-padded to 128
        bool supk = false;
        int kp = (((nk + 3) >> 2) + 7) & ~7;
        for (int k0 = 0; k0 < kp; k0 += 8) {
#pragma unroll
            for (int u = 0; u < 8; ++u) {
                int j = w + 4 * (k0 + u);
                float4 kb = kept_box[j];
                float ka = kept_area[j];
                int kc = kept_cls[j];
                float ix1 = fmaxf(kb.x, cx1), iy1 = fmaxf(kb.y, cy1);
                float ix2 = fminf(kb.z, cx2), iy2 = fminf(kb.w, cy2);
                float inter = fmaxf(ix2 - ix1, 0.f) * fmaxf(iy2 - iy1, 0.f);
                supk |= (kc == cls_c) & (3.f * inter > ka + ca);
            }
        }

        // intra-batch suppression: wave w owns t in [16w, 16w+16)
        uint64_t sbyw = 0;
#pragma unroll
        for (int u = 0; u < 16; ++u) {
            int t = (w << 4) + u;
            ulonglong2 tv = sq[p0 + t];
            uint64_t tkey = tv.x, tmeta = tv.y;
            float ts = key_score(tkey);
            int tcls = (int)(tkey & 0xFFFFu);
            float tx1 = (float)(short)(tmeta & 0xFFFFu);
            float ty1 = (float)(short)((tmeta >> 16) & 0xFFFFu);
            float tx2 = (float)(short)((tmeta >> 32) & 0xFFFFu);
            float ty2 = (float)(short)((tmeta >> 48) & 0xFFFFu);
            float ta = fmaxf(tx2 - tx1, 0.f) * fmaxf(ty2 - ty1, 0.f);
            float ix1 = fmaxf(tx1, cx1), iy1 = fmaxf(ty1, cy1);
            float ix2 = fminf(tx2, cx2), iy2 = fminf(ty2, cy2);
            float inter = fmaxf(ix2 - ix1, 0.f) * fmaxf(iy2 - iy1, 0.f);
            bool sup = (t < lane) && (ts > SCORE_TH) && (tcls == cls_c)
                       && (3.f * inter > ta + ca);
            sbyw |= ((uint64_t)sup) << t;
        }

        uint64_t mk = __ballot(supk);
        if (lane == 0) smask[w] = mk;
        sby[(w << 6) + lane] = sbyw;
        __syncthreads();

        if (w == 0) {
            uint64_t supkAll = smask[0] | smask[1] | smask[2] | smask[3];
            uint64_t supBy = sby[lane] | sby[64 + lane] | sby[128 + lane] | sby[192 + lane];
            bool alive0 = sval && !((supkAll >> lane) & 1ULL);

            uint64_t aliveCand = __ballot(alive0);
            uint64_t aliveMask;
            if (__ballot(supBy != 0ULL) == 0ULL) {
                aliveMask = aliveCand;          // fast path
            } else {
                uint64_t killed = 0;
                for (int t = 0; t < 64; ++t) {
                    uint64_t kill_t = __ballot((supBy >> t) & 1ULL);
                    bool talive = ((aliveCand >> t) & 1ULL) && !((killed >> t) & 1ULL);
                    if (talive) killed |= kill_t;
                }
                aliveMask = aliveCand & ~killed;
            }

            int myrank = __popcll(aliveMask & ((1ULL << lane) - 1ULL));
            bool keepme = ((aliveMask >> lane) & 1ULL) && (nk + myrank < MAXDET);
            if (keepme) {
                int slot = nk + myrank;
                kept_box[slot]  = make_float4(cx1, cy1, cx2, cy2);
                kept_area[slot] = ca;
                kept_cls[slot]  = cls_c;
                out[b * MAXDET + slot] = s;
                out[2 * MAXDET + b * MAXDET + slot] = (float)cls_c;
                float* ob = out + 4 * MAXDET + (size_t)(b * MAXDET + slot) * 4;
                ob[0] = cx1; ob[1] = cy1; ob[2] = cx2; ob[3] = cy2;
            }
            int navail = __popcll(aliveMask);
            int room = MAXDET - nk;
            int nk2 = nk + ((navail < room) ? navail : room);
            uint64_t invalid = __ballot(!sval);
            if (lane == 0) {
                snk = nk2;
                if (nk2 >= MAXDET) sdone = 1;
                else if (invalid) { sneedfb = 1; sdone = 1; }   // exhausted short
            }
        }
    }
    __syncthreads();

    int nk = snk;
    bool need_fb = sneedfb || (!sdone && nk < MAXDET);

    if (tid >= 64) return;   // no barriers below; wave 0 finishes

    // ---- cold exact fallback: repeated max-extraction over all 8192 keys ----
    if (need_fb) {
        const uint64_t* wkb = wk + (size_t)b * NANCH;
        const uint64_t* wmb = wm + (size_t)b * NANCH;
        for (int i = lane; i < NANCH / 64; i += 64) fbmap[i] = 0ULL;
        __builtin_amdgcn_wave_barrier();

        nk = 0;
        Kept K;
        K.cl[0] = K.cl[1] = -1;
        K.x1[0]=K.y1[0]=K.x2[0]=K.y2[0]=K.ar[0]=0.f;
        K.x1[1]=K.y1[1]=K.x2[1]=K.y2[1]=K.ar[1]=0.f;

        for (int iter = 0; iter < NANCH; ++iter) {
            uint64_t mybest = 0; int myq = -1;
            for (int q = lane; q < NANCH; q += 64) {
                bool cons = (fbmap[q >> 6] >> (q & 63)) & 1ULL;
                uint64_t kk = wkb[q];
                if (!cons && kk > mybest) { mybest = kk; myq = q; }
            }
            uint64_t best = mybest;
#pragma unroll
            for (int j = 32; j; j >>= 1) {
                uint64_t o = __shfl_xor(best, j);
                if (o > best) best = o;
            }
            if (best == 0ULL) break;
            float s = key_score(best);
            if (!(s > SCORE_TH)) break;
            uint64_t msk = __ballot(mybest == best);
            int wl = __ffsll((unsigned long long)msk) - 1;
            int q = __shfl(myq, wl);
            if (lane == wl) fbmap[q >> 6] |= (1ULL << (q & 63));
            uint64_t cm = wmb[q];
            nms_try_keep(best, cm, s, lane, nk, K, out, b);
            if (nk == MAXDET) break;
            __builtin_amdgcn_wave_barrier();
        }
    }

    // pad remaining slots with -1
    for (int t = nk + lane; t < MAXDET; t += 64) {
        out[b * MAXDET + t] = -1.f;
        out[2 * MAXDET + b * MAXDET + t] = -1.f;
        float* ob = out + 4 * MAXDET + (size_t)(b * MAXDET + t) * 4;
        ob[0] = -1.f; ob[1] = -1.f; ob[2] = -1.f; ob[3] = -1.f;
    }
}

extern "C" void kernel_launch(void* const* d_in, const int* in_sizes, int n_in,
                              void* d_out, int out_size, void* d_ws, size_t ws_size,
                              hipStream_t stream) {
    (void)in_sizes; (void)n_in; (void)out_size; (void)ws_size;
    const float* cls_heads = (const float*)d_in[0];
    const float* reg_heads = (const float*)d_in[1];
    const float* anchors   = (const float*)d_in[2];
    float* out = (float*)d_out;

    char* w = (char*)d_ws;
    int*        cnt  = (int*)w;                                  // 8 B (zeroed per replay)
    uint64_t*   wk   = (uint64_t*)(w + 1024);                    // 128 KiB
    uint64_t*   wm   = (uint64_t*)(w + 1024 + 131072);           // 128 KiB
    ulonglong2* surv = (ulonglong2*)(w + 1024 + 262144);         // 16 KiB

    hipMemsetAsync(cnt, 0, 2 * sizeof(int), stream);
    decode_kernel<<<dim3(NANCH / ROWS_PB, 2), 256, 0, stream>>>(cls_heads, reg_heads, anchors,
                                                                cnt, wk, wm, surv);
    sort_nms_kernel<<<dim3(2), 256, 0, stream>>>(cnt, wk, wm, surv, out);
}